// Round 7
// baseline (30.043 us; speedup 1.0000x reference)
//
#include <hip/hip_runtime.h>

// 3x3 cross-correlation, padding=1, NCHW, fp32 in/out, bf16 MFMA compute.
// out[b,o,h,w] = bias[o] + sum_{i,c} comb[o, i*16+c] * x[b,c,h+dy_i,w+dx_i]
// B=4, C=16, O=16, H=450, W=480. K = 144 = 9 flows x 16 c, padded to 5x32.
//
// Round 7: 2-phase pipeline (T3 minimal + T14 reg-staging). R6 counters: all
// pipes idle (VALU<10, MFMA~3.5, HBM~30%, occ~20) -> latency convoys.
//  - each block: G=4 row-groups (16 output rows x 96 px), LDS double-buffer
//  - per iter: issue loads(g+1) -> compute(g) -> vmcnt+cvt+ds_write(g+1) -> bar
//  - 580 blocks, 4/CU capacity -> all resident, no scheduling rounds
//  - bijective XCD swizzle (580 = 8*72+4), hg-fastest -> vertical L2 strips

#define HH 450
#define WW 480
#define BB 4
#define CC 16
#define OO 16
#define WT    96                 // output pixels per block (width), 6 tiles
#define WQN   5                  // width groups
#define WIN   100                // staged wi count (w0-1 .. w0+98)
#define RSTG  6                  // staged rows per group
#define ROUT  4                  // output rows per group
#define GPB   4                  // groups per block
#define RBN   29                 // group-quads per column: ceil(113/4)
#define NTILE 6                  // 16-pixel MFMA tiles per row
#define ITEMS (2 * RSTG * WIN)   // 1200 staging items per group
#define HALFI (RSTG * WIN)       // 600
#define NBLK  (BB * WQN * RBN)   // 580

typedef __attribute__((ext_vector_type(8))) short    bf16x8;
typedef __attribute__((ext_vector_type(4))) float    f32x4;
typedef __attribute__((ext_vector_type(4))) unsigned u32x4;

static __device__ __forceinline__ unsigned cvt_pk_bf16(float a, float b) {
    unsigned r;
    asm("v_cvt_pk_bf16_f32 %0, %1, %2" : "=v"(r) : "v"(a), "v"(b));
    return r;   // lo16 = bf16(a), hi16 = bf16(b), RNE
}

__global__ __launch_bounds__(256, 4) void flow_mfma_kernel(
    const float* __restrict__ x, const float* __restrict__ comb,
    const float* __restrict__ bias, float* __restrict__ out)
{
    // [buf][c-half][r*WIN + wi][8 shorts] : 16B rows, 2 x 19200 B = 38400 B
    __shared__ __align__(16) short xs[2][2][RSTG * WIN][8];

    const int tid  = threadIdx.x;
    const int lane = tid & 63;
    const int wv   = tid >> 6;

    // ---- bijective XCD swizzle (580 = 8*72 + 4, m204 formula) ----
    int bid = blockIdx.x;
    int xcd = bid & 7, pos = bid >> 3;
    int L   = (xcd < 4) ? xcd * 73 + pos : 4 * 73 + (xcd - 4) * 72 + pos;
    // decode: L = (b*WQN + wq)*RBN + rb   (rb fastest -> vertical strips)
    int rb  = L % RBN;
    int t2  = L / RBN;
    int wq  = t2 % WQN;
    int b   = t2 / WQN;
    int w0  = wq * WT;

    // ---- A-frags: weights fp32->bf16 once, in VGPRs ----
    const int col = lane & 15;          // pixel-in-tile (B col) / output o (A row)
    const int grp = lane >> 4;          // 0..3
    bf16x8 af[5];
    #pragma unroll
    for (int m = 0; m < 5; ++m) {
        int k0 = m * 32 + grp * 8;
        u32x4 p;
        if (k0 < 144) {
            float4 u = *(const float4*)(comb + col * 144 + k0);
            float4 v = *(const float4*)(comb + col * 144 + k0 + 4);
            p[0] = cvt_pk_bf16(u.x, u.y);
            p[1] = cvt_pk_bf16(u.z, u.w);
            p[2] = cvt_pk_bf16(v.x, v.y);
            p[3] = cvt_pk_bf16(v.z, v.w);
        } else {
            p[0] = p[1] = p[2] = p[3] = 0u;
        }
        af[m] = __builtin_bit_cast(bf16x8, p);
    }
    f32x4 bv = *(const f32x4*)(bias + grp * 4);   // acc init: bias[grp*4+r]

    // ---- per-lane B-frag row offsets (independent of group) ----
    const int fo = grp >> 1;
    const int ch = grp & 1;
    int boff[5];
    #pragma unroll
    for (int m = 0; m < 4; ++m) {
        int i  = 2 * m + fo;
        int ky = i / 3;
        int kx = i % 3;
        boff[m] = (wv + ky) * WIN + col + kx;
    }
    boff[4] = (wv + 2) * WIN + col + 2;      // flow 8 (ky=2, kx=2)

    float fv[5][8];                           // in-flight staging registers

    // phase A: issue global loads for group g into fv (no waits needed yet)
    auto stage_load = [&](int g) {
        int h0 = (rb * GPB + g) * ROUT;
        #pragma unroll
        for (int it = 0; it < 5; ++it) {
            int s = tid + it * 256;
            bool okit = (s < ITEMS);
            int chs = (s >= HALFI) ? 1 : 0;
            int r2  = s - chs * HALFI;        // r*WIN + wi
            int r   = r2 / WIN;
            int wi  = r2 - r * WIN;
            int hy  = h0 - 1 + r;
            int w   = w0 + wi - 1;
            if (okit && ((unsigned)hy < (unsigned)HH) && ((unsigned)w < (unsigned)WW)) {
                const float* xp = x + (((size_t)(b * CC + chs * 8) * HH + hy) * WW + w);
                #pragma unroll
                for (int j = 0; j < 8; ++j)
                    fv[it][j] = xp[(size_t)j * HH * WW];
            } else {
                #pragma unroll
                for (int j = 0; j < 8; ++j) fv[it][j] = 0.0f;
            }
        }
    };

    // phase B: convert + write to LDS buffer `buf`
    auto stage_write = [&](int buf) {
        #pragma unroll
        for (int it = 0; it < 5; ++it) {
            int s = tid + it * 256;
            if (s < ITEMS) {
                int chs = (s >= HALFI) ? 1 : 0;
                int r2  = s - chs * HALFI;
                u32x4 p;
                p[0] = cvt_pk_bf16(fv[it][0], fv[it][1]);
                p[1] = cvt_pk_bf16(fv[it][2], fv[it][3]);
                p[2] = cvt_pk_bf16(fv[it][4], fv[it][5]);
                p[3] = cvt_pk_bf16(fv[it][6], fv[it][7]);
                *(u32x4*)(&xs[buf][chs][r2][0]) = p;
            }
        }
    };

    auto compute = [&](int g, int buf) {
        int h = (rb * GPB + g) * ROUT + wv;   // wave wv owns one row
        if (h >= HH) return;
        #pragma unroll
        for (int t = 0; t < NTILE; ++t) {
            int n0 = t * 16;
            f32x4 acc = bv;
            #pragma unroll
            for (int m = 0; m < 4; ++m) {
                bf16x8 bf = *(const bf16x8*)(&xs[buf][ch][boff[m] + n0][0]);
                acc = __builtin_amdgcn_mfma_f32_16x16x32_bf16(af[m], bf, acc, 0, 0, 0);
            }
            bf16x8 b4;
            if (grp < 2) {
                b4 = *(const bf16x8*)(&xs[buf][ch][boff[4] + n0][0]);
            } else {
                #pragma unroll
                for (int j = 0; j < 8; ++j) b4[j] = 0;
            }
            acc = __builtin_amdgcn_mfma_f32_16x16x32_bf16(af[4], b4, acc, 0, 0, 0);

            float* op = out + (((size_t)(b * OO + grp * 4) * HH + h) * WW + w0 + n0 + col);
            #pragma unroll
            for (int j = 0; j < 4; ++j)
                op[(size_t)j * HH * WW] = acc[j];
        }
    };

    // ---- pipeline: load(0) write(0) bar; {load(g+1) | compute(g) | write(g+1)} bar
    stage_load(0);
    stage_write(0);
    __syncthreads();
    #pragma unroll
    for (int g = 0; g < GPB; ++g) {
        if (g + 1 < GPB) stage_load(g + 1);   // loads in flight under compute
        compute(g, g & 1);
        if (g + 1 < GPB) stage_write((g + 1) & 1);
        __syncthreads();
    }
}

extern "C" void kernel_launch(void* const* d_in, const int* in_sizes, int n_in,
                              void* d_out, int out_size, void* d_ws, size_t ws_size,
                              hipStream_t stream) {
    const float* x    = (const float*)d_in[0];
    const float* comb = (const float*)d_in[1];
    const float* bias = (const float*)d_in[2];
    float* out        = (float*)d_out;

    flow_mfma_kernel<<<NBLK, 256, 0, stream>>>(x, comb, bias, out);
}

// Round 8
// 25.023 us; speedup vs baseline: 1.2006x; 1.2006x over previous
//
#include <hip/hip_runtime.h>

// 3x3 cross-correlation, padding=1, NCHW, fp32 in/out, bf16 MFMA compute.
// out[b,o,h,w] = bias[o] + sum_{i,c} comb[o, i*16+c] * x[b,c,h+dy_i,w+dx_i]
// B=4, C=16, O=16, H=450, W=480. K = 144 = 9 flows x 16 c, padded to 5x32.
//
// Round 8: balanced single-round grid. R7 pipeline regressed (convoyed
// barriers, too few blocks/CU); R6's real bug was 1140 blocks vs 1024
// capacity = 1.11 rounds (occupancy 20% = two-round blend).
//  - ROUT=12/RSTG=14/WT=96: LDS 46.6KB -> 3 blocks/CU, grid 760 = 8*95
//    -> all resident, balanced (248 CU x3 + 8 x2), zero tail rounds
//  - staging via float2 (8 planes x 2w per item): half the load insts of
//    R6's scalar path; 2 contiguous b128 LDS writes, lane stride 32B =
//    conflict-free; 4-aligned pairs are fully in- or out-of-bounds
//  - burst stage -> barrier -> compute (no pipeline; blocks overlap phases)

#define HH 450
#define WW 480
#define BB 4
#define CC 16
#define OO 16
#define WT    96                 // output pixels per block (width), 6 tiles
#define WQN   5                  // width groups
#define WIN   104                // staged wi count (w0-4 .. w0+99)
#define RSTG  14                 // staged rows per block
#define ROUT  12                 // output rows per block
#define HG    38                 // row-groups: ceil(450/12)
#define NTILE 6                  // 16-pixel MFMA tiles per row
#define W2N   (WIN / 2)          // 52 float2 groups per staged row
#define HALFI (RSTG * W2N)       // 728 items per c-half
#define ITEMS (2 * HALFI)        // 1456 staging items
#define NBLK  (BB * WQN * HG)    // 760 = 8 * 95

typedef __attribute__((ext_vector_type(8))) short    bf16x8;
typedef __attribute__((ext_vector_type(4))) float    f32x4;
typedef __attribute__((ext_vector_type(4))) unsigned u32x4;

static __device__ __forceinline__ unsigned cvt_pk_bf16(float a, float b) {
    unsigned r;
    asm("v_cvt_pk_bf16_f32 %0, %1, %2" : "=v"(r) : "v"(a), "v"(b));
    return r;   // lo16 = bf16(a), hi16 = bf16(b), RNE
}

__global__ __launch_bounds__(256, 3) void flow_mfma_kernel(
    const float* __restrict__ x, const float* __restrict__ comb,
    const float* __restrict__ bias, float* __restrict__ out)
{
    // [c-half][r*WIN + wi][8 shorts] : 16B rows, 46592 B -> 3 blocks/CU
    __shared__ __align__(16) short xs[2][RSTG * WIN][8];

    const int tid  = threadIdx.x;
    const int lane = tid & 63;
    const int wv   = tid >> 6;

    // ---- bijective XCD swizzle: 760 = 8*95 exactly ----
    int bid = blockIdx.x;
    int L   = (bid & 7) * 95 + (bid >> 3);
    // decode: L = (b*WQN + wq)*HG + hg  (hg fastest -> vertical L2 strips)
    int hg  = L % HG;
    int t2  = L / HG;
    int wq  = t2 % WQN;
    int b   = t2 / WQN;
    int h0  = hg * ROUT;
    int w0  = wq * WT;

    // ---- A-frags: weights fp32->bf16 once, in VGPRs ----
    const int col = lane & 15;          // pixel-in-tile (B col) / output o (A row)
    const int grp = lane >> 4;          // 0..3
    bf16x8 af[5];
    #pragma unroll
    for (int m = 0; m < 5; ++m) {
        int k0 = m * 32 + grp * 8;
        u32x4 p;
        if (k0 < 144) {
            float4 u = *(const float4*)(comb + col * 144 + k0);
            float4 v = *(const float4*)(comb + col * 144 + k0 + 4);
            p[0] = cvt_pk_bf16(u.x, u.y);
            p[1] = cvt_pk_bf16(u.z, u.w);
            p[2] = cvt_pk_bf16(v.x, v.y);
            p[3] = cvt_pk_bf16(v.z, v.w);
        } else {
            p[0] = p[1] = p[2] = p[3] = 0u;
        }
        af[m] = __builtin_bit_cast(bf16x8, p);
    }
    f32x4 bv = *(const f32x4*)(bias + grp * 4);   // acc init: bias[grp*4+r]

    // ---- stage x -> LDS bf16 ----
    // item s: ch = s >= HALFI; rem = r*W2N + wi2; covers w = w0-4+2*wi2, +1
    auto stage = [&](int s) {
        int ch  = (s >= HALFI) ? 1 : 0;
        int rem = s - ch * HALFI;
        int r   = rem / W2N;
        int wi2 = rem - r * W2N;
        int hy  = h0 - 1 + r;
        int w   = w0 - 4 + wi2 * 2;
        u32x4 p0, p1;
        if (((unsigned)hy < (unsigned)HH) && ((unsigned)w < (unsigned)WW)) {
            const float* xp = x + (((size_t)(b * CC + ch * 8) * HH + hy) * WW + w);
            float fx[8], fy[8];
            #pragma unroll
            for (int j = 0; j < 8; ++j) {
                float2 v = *(const float2*)(xp + (size_t)j * HH * WW);
                fx[j] = v.x; fy[j] = v.y;
            }
            p0[0] = cvt_pk_bf16(fx[0], fx[1]);
            p0[1] = cvt_pk_bf16(fx[2], fx[3]);
            p0[2] = cvt_pk_bf16(fx[4], fx[5]);
            p0[3] = cvt_pk_bf16(fx[6], fx[7]);
            p1[0] = cvt_pk_bf16(fy[0], fy[1]);
            p1[1] = cvt_pk_bf16(fy[2], fy[3]);
            p1[2] = cvt_pk_bf16(fy[4], fy[5]);
            p1[3] = cvt_pk_bf16(fy[6], fy[7]);
        } else {
            p0[0] = p0[1] = p0[2] = p0[3] = 0u;
            p1[0] = p1[1] = p1[2] = p1[3] = 0u;
        }
        int r2 = r * WIN + wi2 * 2;
        *(u32x4*)(&xs[ch][r2][0])     = p0;
        *(u32x4*)(&xs[ch][r2 + 1][0]) = p1;
    };
    #pragma unroll
    for (int it = 0; it < 5; ++it)        // 5*256 = 1280 items
        stage(tid + it * 256);
    if (tid < ITEMS - 5 * 256)            // tail: 176 items
        stage(tid + 5 * 256);
    __syncthreads();

    // ---- compute: wave wv owns output rows h0 + 3wv .. h0 + 3wv + 2 ----
    const int fo = grp >> 1;
    const int ch = grp & 1;
    #pragma unroll
    for (int rr = 0; rr < 3; ++rr) {
        int r = 3 * wv + rr;              // row within group
        int h = h0 + r;
        if (h >= HH) continue;

        // pixel w0+n0+col+kx-1 -> staged wi = n0+col+kx+3
        int boff[5];
        #pragma unroll
        for (int m = 0; m < 4; ++m) {
            int i  = 2 * m + fo;
            int ky = i / 3;
            int kx = i % 3;
            boff[m] = (r + ky) * WIN + col + kx + 3;
        }
        boff[4] = (r + 2) * WIN + col + 2 + 3;   // flow 8 (ky=2, kx=2)

        #pragma unroll
        for (int t = 0; t < NTILE; ++t) {
            int n0 = t * 16;
            f32x4 acc = bv;
            #pragma unroll
            for (int m = 0; m < 4; ++m) {
                bf16x8 bf = *(const bf16x8*)(&xs[ch][boff[m] + n0][0]);
                acc = __builtin_amdgcn_mfma_f32_16x16x32_bf16(af[m], bf, acc, 0, 0, 0);
            }
            bf16x8 b4;
            if (grp < 2) {
                b4 = *(const bf16x8*)(&xs[ch][boff[4] + n0][0]);
            } else {
                #pragma unroll
                for (int j = 0; j < 8; ++j) b4[j] = 0;
            }
            acc = __builtin_amdgcn_mfma_f32_16x16x32_bf16(af[4], b4, acc, 0, 0, 0);

            // D: col = pixel, row o = grp*4 + j
            float* op = out + (((size_t)(b * OO + grp * 4) * HH + h) * WW + w0 + n0 + col);
            #pragma unroll
            for (int j = 0; j < 4; ++j)
                op[(size_t)j * HH * WW] = acc[j];
        }
    }
}

extern "C" void kernel_launch(void* const* d_in, const int* in_sizes, int n_in,
                              void* d_out, int out_size, void* d_ws, size_t ws_size,
                              hipStream_t stream) {
    const float* x    = (const float*)d_in[0];
    const float* comb = (const float*)d_in[1];
    const float* bias = (const float*)d_in[2];
    float* out        = (float*)d_out;

    flow_mfma_kernel<<<NBLK, 256, 0, stream>>>(x, comb, bias, out);
}